// Round 3
// baseline (829.557 us; speedup 1.0000x reference)
//
#include <hip/hip_runtime.h>

typedef unsigned short u16;
typedef unsigned int   u32;
typedef __bf16  bf16x8 __attribute__((ext_vector_type(8)));
typedef float   f32x4  __attribute__((ext_vector_type(4)));
typedef u16     u16x8  __attribute__((ext_vector_type(8)));
typedef u16     u16x4  __attribute__((ext_vector_type(4)));

__device__ __forceinline__ float bf2f(u16 v) {
    union { u32 i; float f; } u; u.i = (u32)v << 16; return u.f;
}
__device__ __forceinline__ u16 f2bf(float f) {
    union { float f; u32 i; } u; u.f = f;
    u32 r = (u.i + 0x7FFFu + ((u.i >> 16) & 1u)) >> 16;
    return (u16)r;
}
__device__ __forceinline__ bf16x8 ld8(const u16* p) {
    return __builtin_bit_cast(bf16x8, *(const u16x8*)p);
}

// ---------------------------------------------------------------------------
// dtype detect: low 16 bits of the first 64 words of x. bf16 data -> those are
// N(0,1) samples (in [2^-10,16]); fp32 data -> mantissa noise (~6% pass).
// flag = 1 means fp32 inputs.
// ---------------------------------------------------------------------------
__global__ void detect_kernel(const u16* __restrict__ x, int* __restrict__ flag) {
    if (threadIdx.x == 0 && blockIdx.x == 0) {
        int plausible = 0;
        for (int j = 0; j < 64; j++) {
            float a = fabsf(bf2f(x[2 * j]));
            if (a >= 0.0009765625f && a <= 16.0f) plausible++;
        }
        *flag = (plausible >= 32) ? 0 : 1;
    }
}

// ---------------------------------------------------------------------------
// fp32->bf16 convert (or bf16 passthrough copy), 4 elems/thread, grid-stride.
// ---------------------------------------------------------------------------
__global__ __launch_bounds__(256) void convert_kernel(
    const void* __restrict__ src, u16* __restrict__ dst, int n,
    const int* __restrict__ flag)
{
    int fp32 = *flag;
    int stride = gridDim.x * 256 * 4;
    for (int i = (blockIdx.x * 256 + threadIdx.x) * 4; i < n; i += stride) {
        if (fp32) {
            float4 v = *(const float4*)((const float*)src + i);
            u16x4 o = { f2bf(v.x), f2bf(v.y), f2bf(v.z), f2bf(v.w) };
            *(u16x4*)(dst + i) = o;
        } else {
            *(u16x4*)(dst + i) = *(const u16x4*)((const u16*)src + i);
        }
    }
}

// ---------------------------------------------------------------------------
// rel-pos bias pre-gather: layout [h][tm][tn][c=n%16][r=m%16], n>=196 masked.
// Reads the CONVERTED bf16 table.
// ---------------------------------------------------------------------------
__global__ __launch_bounds__(256) void rpb_prep(const u16* __restrict__ table,
                                                u16* __restrict__ RPB) {
    int idx = blockIdx.x * 256 + threadIdx.x;
    if (idx >= 12 * 13 * 13 * 256) return;
    int r  = idx & 15;
    int c  = (idx >> 4) & 15;
    int q  = idx >> 8;
    int tn = q % 13;
    int q2 = q / 13;
    int tm = q2 % 13;
    int h  = q2 / 13;
    int m = tm * 16 + r, n = tn * 16 + c;
    float val;
    if (n >= 196) {
        val = -30000.0f;                    // mask -> exp underflows to 0
    } else {
        int mc = m > 195 ? 195 : m;         // clamp garbage m-rows
        int i1 = mc / 14, j1 = mc % 14, i2 = n / 14, j2 = n % 14;
        int t = (i1 - i2 + 13) * 27 + (j1 - j2 + 13);
        val = bf2f(table[t * 12 + h]);
    }
    RPB[idx] = f2bf(val);
}

// ---------------------------------------------------------------------------
// bf16 GEMM (register staging + ds_write): C[m][n] = sum_k A[m][k]*B[n][k]
// MODE 0: qkv (bias0=q_bias, bias1=v_bias bf16, q-scale 0.125), bf16 store
// MODE 1: proj (bias0=proj_b bf16), window-reverse permuted store,
//         output dtype selected by *flag (fp32 or bf16)
// ---------------------------------------------------------------------------
template <int MODE, int NCOLS>
__global__ __launch_bounds__(256) void gemm_kernel(
    const u16* __restrict__ A, const u16* __restrict__ Bw,
    const u16* __restrict__ bias0, const u16* __restrict__ bias1,
    void* __restrict__ Cc, const int* __restrict__ flag)
{
    __shared__ __align__(16) u16 As[128][32];
    __shared__ __align__(16) u16 Bs[128][32];
    __shared__ __align__(16) u16 rb[4][64][72];   // epilogue repack

    const int tid  = threadIdx.x;
    const int wave = tid >> 6, lane = tid & 63;
    const int quad = lane >> 4, l16 = lane & 15;
    const int bm = blockIdx.y * 128, bn = blockIdx.x * 128;
    const int wm = (wave >> 1) * 64, wn = (wave & 1) * 64;

    const int sr = wave * 32 + (lane >> 2);   // staging row (this lane)
    const int sk = (lane & 3) * 8;            // staging k-offset

    const u16* ga = A  + (size_t)(bm + sr) * 768 + sk;
    const u16* gb = Bw + (size_t)(bn + sr) * 768 + sk;

    f32x4 acc[4][4] = {};

    u16x8 va0 = *(const u16x8*)(ga);
    u16x8 va1 = *(const u16x8*)(ga + 16 * 768);
    u16x8 vb0 = *(const u16x8*)(gb);
    u16x8 vb1 = *(const u16x8*)(gb + 16 * 768);

    for (int k0 = 0; k0 < 768; k0 += 32) {
        __syncthreads();                      // prior iteration's reads done
        *(u16x8*)&As[sr][sk]      = va0;
        *(u16x8*)&As[sr + 16][sk] = va1;
        *(u16x8*)&Bs[sr][sk]      = vb0;
        *(u16x8*)&Bs[sr + 16][sk] = vb1;
        __syncthreads();
        if (k0 + 32 < 768) {                  // prefetch next slab
            va0 = *(const u16x8*)(ga + k0 + 32);
            va1 = *(const u16x8*)(ga + k0 + 32 + 16 * 768);
            vb0 = *(const u16x8*)(gb + k0 + 32);
            vb1 = *(const u16x8*)(gb + k0 + 32 + 16 * 768);
        }
        bf16x8 af[4], bfr[4];
#pragma unroll
        for (int i = 0; i < 4; i++) af[i]  = ld8(&As[wm + i * 16 + l16][quad * 8]);
#pragma unroll
        for (int i = 0; i < 4; i++) bfr[i] = ld8(&Bs[wn + i * 16 + l16][quad * 8]);
#pragma unroll
        for (int mi = 0; mi < 4; mi++)
#pragma unroll
            for (int ni = 0; ni < 4; ni++)
                acc[mi][ni] = __builtin_amdgcn_mfma_f32_16x16x32_bf16(
                    af[mi], bfr[ni], acc[mi][ni], 0, 0, 0);
    }

    // epilogue: bias/scale -> bf16 repack -> wide stores
    float bs[4], scl[4];
#pragma unroll
    for (int ni = 0; ni < 4; ni++) {
        int col = bn + wn + ni * 16 + l16;
        if (MODE == 0) {
            if (col < 768)       { bs[ni] = bf2f(bias0[col]);        scl[ni] = 0.125f; }
            else if (col < 1536) { bs[ni] = 0.f;                     scl[ni] = 1.f; }
            else                 { bs[ni] = bf2f(bias1[col - 1536]); scl[ni] = 1.f; }
        } else {
            bs[ni] = bf2f(bias0[col]); scl[ni] = 1.f;
        }
    }
#pragma unroll
    for (int mi = 0; mi < 4; mi++)
#pragma unroll
        for (int ni = 0; ni < 4; ni++)
#pragma unroll
            for (int r = 0; r < 4; r++)
                rb[wave][mi * 16 + quad * 4 + r][ni * 16 + l16] =
                    f2bf((acc[mi][ni][r] + bs[ni]) * scl[ni]);
    __asm__ volatile("s_waitcnt lgkmcnt(0)" ::: "memory");

    const int fp32out = (MODE == 1) ? *flag : 0;
#pragma unroll
    for (int i = 0; i < 8; i++) {
        int row = i * 8 + (lane >> 3);
        int cg  = (lane & 7) * 8;
        u16x8 val = *(const u16x8*)&rb[wave][row][cg];
        int gm = bm + wm + row;
        int gn = bn + wn + cg;
        size_t off;
        if (MODE == 0) {
            off = (size_t)gm * NCOLS + gn;
        } else {
            int wwin = gm / 196, t = gm % 196;
            int b2 = wwin >> 4, wh2 = (wwin >> 2) & 3, ww2 = wwin & 3;
            int ti = t / 14, tj = t % 14;
            int g = b2 * 3136 + (wh2 * 14 + ti) * 56 + ww2 * 14 + tj;
            off = (size_t)g * NCOLS + gn;
        }
        if (MODE == 1 && fp32out) {
            float* outf = (float*)Cc;
            float4 lo = { bf2f(val[0]), bf2f(val[1]), bf2f(val[2]), bf2f(val[3]) };
            float4 hi = { bf2f(val[4]), bf2f(val[5]), bf2f(val[6]), bf2f(val[7]) };
            *(float4*)&outf[off]     = lo;
            *(float4*)&outf[off + 4] = hi;
        } else {
            *(u16x8*)&((u16*)Cc)[off] = val;
        }
    }
}

// ---------------------------------------------------------------------------
// Window attention: one block per (window, head). 4 waves, m-tiles strided.
// All-bf16 (reads qkv intermediate).
// ---------------------------------------------------------------------------
__global__ __launch_bounds__(256) void attn_kernel(
    const u16* __restrict__ QKV, const u16* __restrict__ RPB, u16* __restrict__ O)
{
    __shared__ __align__(16) u16 k_s[208][72];   // +8 pad for LDS banking
    __shared__ __align__(16) u16 v_t[64][224];   // transposed V: [d][token]
    __shared__ __align__(16) u16 p_s[4][16][40]; // per-wave P chunk (C/D -> A layout)

    const int tid  = threadIdx.x;
    const int wave = tid >> 6, lane = tid & 63;
    const int quad = lane >> 4, l16 = lane & 15;
    const int w = blockIdx.x / 12, h = blockIdx.x % 12;
    const int b = w >> 4, wh = (w >> 2) & 3, ww = w & 3;
    const int gbase = b * 3136 + wh * 14 * 56 + ww * 14;

    for (int c = tid; c < 1568; c += 256) {
        int tok = c >> 3, dg = c & 7;
        int ti = tok / 14, tj = tok % 14;
        size_t grow = (size_t)(gbase + ti * 56 + tj) * 2304 + h * 64 + dg * 8;
        uint4 kk = *(const uint4*)&QKV[grow + 768];
        *(uint4*)&k_s[tok][dg * 8] = kk;
        uint4 vv = *(const uint4*)&QKV[grow + 1536];
        const u16* pv = (const u16*)&vv;
#pragma unroll
        for (int j = 0; j < 8; j++) v_t[dg * 8 + j][tok] = pv[j];
    }
    for (int c = tid; c < 12 * 64; c += 256) k_s[196 + (c >> 6)][c & 63] = 0;
    for (int c = tid; c < 64 * 28; c += 256) v_t[c / 28][196 + c % 28] = 0;
    __syncthreads();

    for (int tm = wave; tm < 13; tm += 4) {
        int tq = tm * 16 + l16; if (tq > 195) tq = 195;
        int qi = tq / 14, qj = tq % 14;
        size_t qoff = (size_t)(gbase + qi * 56 + qj) * 2304 + h * 64 + quad * 8;
        bf16x8 aq0 = ld8(&QKV[qoff]);
        bf16x8 aq1 = ld8(&QKV[qoff + 32]);

        f32x4 sc[13];
#pragma unroll
        for (int tn = 0; tn < 13; tn++) {
            bf16x8 bk0 = ld8(&k_s[tn * 16 + l16][quad * 8]);
            bf16x8 bk1 = ld8(&k_s[tn * 16 + l16][32 + quad * 8]);
            f32x4 z = {};
            z = __builtin_amdgcn_mfma_f32_16x16x32_bf16(aq0, bk0, z, 0, 0, 0);
            sc[tn] = __builtin_amdgcn_mfma_f32_16x16x32_bf16(aq1, bk1, z, 0, 0, 0);
        }
#pragma unroll
        for (int tn = 0; tn < 13; tn++) {
            const u16* rp = &RPB[((((h * 13 + tm) * 13 + tn) * 16 + l16) << 4) + quad * 4];
#pragma unroll
            for (int r = 0; r < 4; r++) sc[tn][r] += bf2f(rp[r]);
        }
        float inv[4];
#pragma unroll
        for (int r = 0; r < 4; r++) {
            float m = -3.0e38f;
#pragma unroll
            for (int tn = 0; tn < 13; tn++) m = fmaxf(m, sc[tn][r]);
#pragma unroll
            for (int d = 1; d < 16; d <<= 1) m = fmaxf(m, __shfl_xor(m, d, 64));
            float s = 0.f;
#pragma unroll
            for (int tn = 0; tn < 13; tn++) {
                float e = __expf(sc[tn][r] - m);
                sc[tn][r] = e; s += e;
            }
#pragma unroll
            for (int d = 1; d < 16; d <<= 1) s += __shfl_xor(s, d, 64);
            inv[r] = 1.f / s;
        }
        f32x4 oc[4] = {};
#pragma unroll
        for (int s7 = 0; s7 < 7; s7++) {
#pragma unroll
            for (int tt = 0; tt < 2; tt++) {
                int tn = 2 * s7 + tt;
#pragma unroll
                for (int r = 0; r < 4; r++) {
                    float pv = (tn < 13) ? sc[tn][r] * inv[r] : 0.f;
                    p_s[wave][quad * 4 + r][tt * 16 + l16] = f2bf(pv);
                }
            }
            __asm__ volatile("s_waitcnt lgkmcnt(0)" ::: "memory");
            bf16x8 ap = ld8(&p_s[wave][l16][quad * 8]);
#pragma unroll
            for (int dt = 0; dt < 4; dt++) {
                bf16x8 bv = ld8(&v_t[dt * 16 + l16][s7 * 32 + quad * 8]);
                oc[dt] = __builtin_amdgcn_mfma_f32_16x16x32_bf16(ap, bv, oc[dt], 0, 0, 0);
            }
        }
#pragma unroll
        for (int dt = 0; dt < 4; dt++)
#pragma unroll
            for (int r = 0; r < 4; r++) {
                int t = tm * 16 + quad * 4 + r;
                if (t < 196)
                    O[(size_t)(w * 196 + t) * 768 + h * 64 + dt * 16 + l16] = f2bf(oc[dt][r]);
            }
    }
}

// ---------------------------------------------------------------------------
extern "C" void kernel_launch(void* const* d_in, const int* in_sizes, int n_in,
                              void* d_out, int out_size, void* d_ws, size_t ws_size,
                              hipStream_t stream) {
    char* ws = (char*)d_ws;
    // workspace layout (xbf aliases attnout: x dead before attn writes)
    u16* qkv     = (u16*)(ws);                        // 231,211,008 B
    u16* xbf     = (u16*)(ws + 231211008);            //  77,070,336 B (= attnout)
    u16* attnout = xbf;
    u16* wqkv_bf = (u16*)(ws + 308281344);            //   3,538,944 B
    u16* wproj_bf= (u16*)(ws + 311820288);            //   1,179,648 B
    u16* rpb     = (u16*)(ws + 312999936);            //   1,038,336 B
    u16* qb_bf   = (u16*)(ws + 314038272);            //       1,536 B
    u16* vb_bf   = (u16*)(ws + 314039808);
    u16* pb_bf   = (u16*)(ws + 314041344);
    u16* tbl_bf  = (u16*)(ws + 314042880);            //      17,496 B
    int* flag    = (int*)(ws + 314060384);

    detect_kernel<<<1, 64, 0, stream>>>((const u16*)d_in[0], flag);
    convert_kernel<<<4096, 256, 0, stream>>>(d_in[0], xbf,      16 * 3136 * 768, flag);
    convert_kernel<<<1728, 256, 0, stream>>>(d_in[1], wqkv_bf,  2304 * 768,      flag);
    convert_kernel<<< 576, 256, 0, stream>>>(d_in[5], wproj_bf, 768 * 768,       flag);
    convert_kernel<<<   1, 256, 0, stream>>>(d_in[2], qb_bf,    768,             flag);
    convert_kernel<<<   1, 256, 0, stream>>>(d_in[3], vb_bf,    768,             flag);
    convert_kernel<<<   1, 256, 0, stream>>>(d_in[6], pb_bf,    768,             flag);
    convert_kernel<<<   9, 256, 0, stream>>>(d_in[4], tbl_bf,   729 * 12,        flag);

    rpb_prep<<<2028, 256, 0, stream>>>(tbl_bf, rpb);
    gemm_kernel<0, 2304><<<dim3(18, 392), 256, 0, stream>>>(
        xbf, wqkv_bf, qb_bf, vb_bf, qkv, flag);
    attn_kernel<<<3072, 256, 0, stream>>>(qkv, rpb, attnout);
    gemm_kernel<1, 768><<<dim3(6, 392), 256, 0, stream>>>(
        attnout, wproj_bf, pb_bf, pb_bf, d_out, flag);
}

// Round 4
// 807.017 us; speedup vs baseline: 1.0279x; 1.0279x over previous
//
#include <hip/hip_runtime.h>

typedef unsigned short u16;
typedef unsigned int   u32;
typedef __bf16  bf16x8 __attribute__((ext_vector_type(8)));
typedef float   f32x4  __attribute__((ext_vector_type(4)));
typedef u16     u16x8  __attribute__((ext_vector_type(8)));
typedef u16     u16x4  __attribute__((ext_vector_type(4)));

__device__ __forceinline__ float bf2f(u16 v) {
    union { u32 i; float f; } u; u.i = (u32)v << 16; return u.f;
}
__device__ __forceinline__ u16 f2bf(float f) {
    union { float f; u32 i; } u; u.f = f;
    u32 r = (u.i + 0x7FFFu + ((u.i >> 16) & 1u)) >> 16;
    return (u16)r;
}
__device__ __forceinline__ bf16x8 ld8(const u16* p) {
    return __builtin_bit_cast(bf16x8, *(const u16x8*)p);
}
__device__ __forceinline__ void gload16(const void* g, void* l) {
    __builtin_amdgcn_global_load_lds((__attribute__((address_space(1))) void*)g,
                                     (__attribute__((address_space(3))) void*)l, 16, 0, 0);
}

// ---------------------------------------------------------------------------
// dtype detect: low 16 bits of the first 64 words of x. bf16 data -> those are
// N(0,1) samples; fp32 data -> mantissa noise. flag = 1 means fp32 inputs.
// ---------------------------------------------------------------------------
__global__ void detect_kernel(const u16* __restrict__ x, int* __restrict__ flag) {
    if (threadIdx.x == 0 && blockIdx.x == 0) {
        int plausible = 0;
        for (int j = 0; j < 64; j++) {
            float a = fabsf(bf2f(x[2 * j]));
            if (a >= 0.0009765625f && a <= 16.0f) plausible++;
        }
        *flag = (plausible >= 32) ? 0 : 1;
    }
}

// ---------------------------------------------------------------------------
// fp32->bf16 convert (or bf16 passthrough copy), 4 elems/thread, grid-stride.
// ---------------------------------------------------------------------------
__global__ __launch_bounds__(256) void convert_kernel(
    const void* __restrict__ src, u16* __restrict__ dst, int n,
    const int* __restrict__ flag)
{
    int fp32 = *flag;
    int stride = gridDim.x * 256 * 4;
    for (int i = (blockIdx.x * 256 + threadIdx.x) * 4; i < n; i += stride) {
        if (fp32) {
            float4 v = *(const float4*)((const float*)src + i);
            u16x4 o = { f2bf(v.x), f2bf(v.y), f2bf(v.z), f2bf(v.w) };
            *(u16x4*)(dst + i) = o;
        } else {
            *(u16x4*)(dst + i) = *(const u16x4*)((const u16*)src + i);
        }
    }
}

// ---------------------------------------------------------------------------
// rel-pos bias pre-gather: layout [h][tm][tn][c=n%16][r=m%16], n>=196 masked.
// ---------------------------------------------------------------------------
__global__ __launch_bounds__(256) void rpb_prep(const u16* __restrict__ table,
                                                u16* __restrict__ RPB) {
    int idx = blockIdx.x * 256 + threadIdx.x;
    if (idx >= 12 * 13 * 13 * 256) return;
    int r  = idx & 15;
    int c  = (idx >> 4) & 15;
    int q  = idx >> 8;
    int tn = q % 13;
    int q2 = q / 13;
    int tm = q2 % 13;
    int h  = q2 / 13;
    int m = tm * 16 + r, n = tn * 16 + c;
    float val;
    if (n >= 196) {
        val = -30000.0f;                    // mask -> exp underflows to 0
    } else {
        int mc = m > 195 ? 195 : m;         // clamp garbage m-rows
        int i1 = mc / 14, j1 = mc % 14, i2 = n / 14, j2 = n % 14;
        int t = (i1 - i2 + 13) * 27 + (j1 - j2 + 13);
        val = bf2f(table[t * 12 + h]);
    }
    RPB[idx] = f2bf(val);
}

// ---------------------------------------------------------------------------
// bf16 GEMM, m97-style global_load_lds width-16 staging:
// C[m][n] = sum_k A[m][k]*B[n][k]  (+bias, scale)
// MODE 0: qkv (bias0=q_bias, bias1=v_bias, q-scale 0.125), bf16 store
// MODE 1: proj (bias0=proj_b), window-reverse permuted store, dtype by *flag
// ---------------------------------------------------------------------------
template <int MODE, int NCOLS>
__global__ __launch_bounds__(256) void gemm_kernel(
    const u16* __restrict__ A, const u16* __restrict__ Bw,
    const u16* __restrict__ bias0, const u16* __restrict__ bias1,
    void* __restrict__ Cc, const int* __restrict__ flag)
{
    __shared__ __align__(16) u16 As[128][32];
    __shared__ __align__(16) u16 Bs[128][32];
    __shared__ __align__(16) u16 rb[4][64][72];   // epilogue repack

    const int tid  = threadIdx.x;
    const int wave = tid >> 6, lane = tid & 63;
    const int quad = lane >> 4, l16 = lane & 15;
    const int bm = blockIdx.y * 128, bn = blockIdx.x * 128;
    const int wm = (wave >> 1) * 64, wn = (wave & 1) * 64;

    const int sr = wave * 32 + (lane >> 2);   // staging row (this lane's deposit)
    const int sk = (lane & 3) * 8;            // staging k-offset

    const u16* ga = A  + (size_t)(bm + sr) * 768 + sk;
    const u16* gb = Bw + (size_t)(bn + sr) * 768 + sk;
    u16* lA0 = &As[wave * 32][0];             // wave-uniform LDS bases
    u16* lA1 = &As[wave * 32 + 16][0];
    u16* lB0 = &Bs[wave * 32][0];
    u16* lB1 = &Bs[wave * 32 + 16][0];

    f32x4 acc[4][4] = {};

    for (int k0 = 0; k0 < 768; k0 += 32) {
        __syncthreads();                      // prior iteration's LDS reads done
        gload16(ga + k0,            lA0);
        gload16(ga + k0 + 16 * 768, lA1);
        gload16(gb + k0,            lB0);
        gload16(gb + k0 + 16 * 768, lB1);
        __syncthreads();                      // drains vmcnt (deposit complete)
        bf16x8 af[4], bfr[4];
#pragma unroll
        for (int i = 0; i < 4; i++) af[i]  = ld8(&As[wm + i * 16 + l16][quad * 8]);
#pragma unroll
        for (int i = 0; i < 4; i++) bfr[i] = ld8(&Bs[wn + i * 16 + l16][quad * 8]);
#pragma unroll
        for (int mi = 0; mi < 4; mi++)
#pragma unroll
            for (int ni = 0; ni < 4; ni++)
                acc[mi][ni] = __builtin_amdgcn_mfma_f32_16x16x32_bf16(
                    af[mi], bfr[ni], acc[mi][ni], 0, 0, 0);
    }

    // epilogue: bias/scale -> bf16 repack -> wide stores
    float bs[4], scl[4];
#pragma unroll
    for (int ni = 0; ni < 4; ni++) {
        int col = bn + wn + ni * 16 + l16;
        if (MODE == 0) {
            if (col < 768)       { bs[ni] = bf2f(bias0[col]);        scl[ni] = 0.125f; }
            else if (col < 1536) { bs[ni] = 0.f;                     scl[ni] = 1.f; }
            else                 { bs[ni] = bf2f(bias1[col - 1536]); scl[ni] = 1.f; }
        } else {
            bs[ni] = bf2f(bias0[col]); scl[ni] = 1.f;
        }
    }
#pragma unroll
    for (int mi = 0; mi < 4; mi++)
#pragma unroll
        for (int ni = 0; ni < 4; ni++)
#pragma unroll
            for (int r = 0; r < 4; r++)
                rb[wave][mi * 16 + quad * 4 + r][ni * 16 + l16] =
                    f2bf((acc[mi][ni][r] + bs[ni]) * scl[ni]);
    __asm__ volatile("s_waitcnt lgkmcnt(0)" ::: "memory");

    const int fp32out = (MODE == 1) ? *flag : 0;
#pragma unroll
    for (int i = 0; i < 8; i++) {
        int row = i * 8 + (lane >> 3);
        int cg  = (lane & 7) * 8;
        u16x8 val = *(const u16x8*)&rb[wave][row][cg];
        int gm = bm + wm + row;
        int gn = bn + wn + cg;
        size_t off;
        if (MODE == 0) {
            off = (size_t)gm * NCOLS + gn;
        } else {
            int wwin = gm / 196, t = gm % 196;
            int b2 = wwin >> 4, wh2 = (wwin >> 2) & 3, ww2 = wwin & 3;
            int ti = t / 14, tj = t % 14;
            int g = b2 * 3136 + (wh2 * 14 + ti) * 56 + ww2 * 14 + tj;
            off = (size_t)g * NCOLS + gn;
        }
        if (MODE == 1 && fp32out) {
            float* outf = (float*)Cc;
            float4 lo = { bf2f(val[0]), bf2f(val[1]), bf2f(val[2]), bf2f(val[3]) };
            float4 hi = { bf2f(val[4]), bf2f(val[5]), bf2f(val[6]), bf2f(val[7]) };
            *(float4*)&outf[off]     = lo;
            *(float4*)&outf[off + 4] = hi;
        } else {
            *(u16x8*)&((u16*)Cc)[off] = val;
        }
    }
}

// ---------------------------------------------------------------------------
// Window attention: one block per (window, head). 4 waves, m-tiles strided.
// ---------------------------------------------------------------------------
__global__ __launch_bounds__(256) void attn_kernel(
    const u16* __restrict__ QKV, const u16* __restrict__ RPB, u16* __restrict__ O)
{
    __shared__ __align__(16) u16 k_s[208][72];   // +8 pad for LDS banking
    __shared__ __align__(16) u16 v_t[64][224];   // transposed V: [d][token]
    __shared__ __align__(16) u16 p_s[4][16][40]; // per-wave P chunk (C/D -> A layout)

    const int tid  = threadIdx.x;
    const int wave = tid >> 6, lane = tid & 63;
    const int quad = lane >> 4, l16 = lane & 15;
    const int w = blockIdx.x / 12, h = blockIdx.x % 12;
    const int b = w >> 4, wh = (w >> 2) & 3, ww = w & 3;
    const int gbase = b * 3136 + wh * 14 * 56 + ww * 14;

    for (int c = tid; c < 1568; c += 256) {
        int tok = c >> 3, dg = c & 7;
        int ti = tok / 14, tj = tok % 14;
        size_t grow = (size_t)(gbase + ti * 56 + tj) * 2304 + h * 64 + dg * 8;
        uint4 kk = *(const uint4*)&QKV[grow + 768];
        *(uint4*)&k_s[tok][dg * 8] = kk;
        uint4 vv = *(const uint4*)&QKV[grow + 1536];
        const u16* pv = (const u16*)&vv;
#pragma unroll
        for (int j = 0; j < 8; j++) v_t[dg * 8 + j][tok] = pv[j];
    }
    for (int c = tid; c < 12 * 64; c += 256) k_s[196 + (c >> 6)][c & 63] = 0;
    for (int c = tid; c < 64 * 28; c += 256) v_t[c / 28][196 + c % 28] = 0;
    __syncthreads();

    for (int tm = wave; tm < 13; tm += 4) {
        int tq = tm * 16 + l16; if (tq > 195) tq = 195;
        int qi = tq / 14, qj = tq % 14;
        size_t qoff = (size_t)(gbase + qi * 56 + qj) * 2304 + h * 64 + quad * 8;
        bf16x8 aq0 = ld8(&QKV[qoff]);
        bf16x8 aq1 = ld8(&QKV[qoff + 32]);

        f32x4 sc[13];
#pragma unroll
        for (int tn = 0; tn < 13; tn++) {
            bf16x8 bk0 = ld8(&k_s[tn * 16 + l16][quad * 8]);
            bf16x8 bk1 = ld8(&k_s[tn * 16 + l16][32 + quad * 8]);
            f32x4 z = {};
            z = __builtin_amdgcn_mfma_f32_16x16x32_bf16(aq0, bk0, z, 0, 0, 0);
            sc[tn] = __builtin_amdgcn_mfma_f32_16x16x32_bf16(aq1, bk1, z, 0, 0, 0);
        }
#pragma unroll
        for (int tn = 0; tn < 13; tn++) {
            const u16* rp = &RPB[((((h * 13 + tm) * 13 + tn) * 16 + l16) << 4) + quad * 4];
#pragma unroll
            for (int r = 0; r < 4; r++) sc[tn][r] += bf2f(rp[r]);
        }
        float inv[4];
#pragma unroll
        for (int r = 0; r < 4; r++) {
            float m = -3.0e38f;
#pragma unroll
            for (int tn = 0; tn < 13; tn++) m = fmaxf(m, sc[tn][r]);
#pragma unroll
            for (int d = 1; d < 16; d <<= 1) m = fmaxf(m, __shfl_xor(m, d, 64));
            float s = 0.f;
#pragma unroll
            for (int tn = 0; tn < 13; tn++) {
                float e = __expf(sc[tn][r] - m);
                sc[tn][r] = e; s += e;
            }
#pragma unroll
            for (int d = 1; d < 16; d <<= 1) s += __shfl_xor(s, d, 64);
            inv[r] = 1.f / s;
        }
        f32x4 oc[4] = {};
#pragma unroll
        for (int s7 = 0; s7 < 7; s7++) {
#pragma unroll
            for (int tt = 0; tt < 2; tt++) {
                int tn = 2 * s7 + tt;
#pragma unroll
                for (int r = 0; r < 4; r++) {
                    float pv = (tn < 13) ? sc[tn][r] * inv[r] : 0.f;
                    p_s[wave][quad * 4 + r][tt * 16 + l16] = f2bf(pv);
                }
            }
            __asm__ volatile("s_waitcnt lgkmcnt(0)" ::: "memory");
            bf16x8 ap = ld8(&p_s[wave][l16][quad * 8]);
#pragma unroll
            for (int dt = 0; dt < 4; dt++) {
                bf16x8 bv = ld8(&v_t[dt * 16 + l16][s7 * 32 + quad * 8]);
                oc[dt] = __builtin_amdgcn_mfma_f32_16x16x32_bf16(ap, bv, oc[dt], 0, 0, 0);
            }
        }
#pragma unroll
        for (int dt = 0; dt < 4; dt++)
#pragma unroll
            for (int r = 0; r < 4; r++) {
                int t = tm * 16 + quad * 4 + r;
                if (t < 196)
                    O[(size_t)(w * 196 + t) * 768 + h * 64 + dt * 16 + l16] = f2bf(oc[dt][r]);
            }
    }
}

// ---------------------------------------------------------------------------
extern "C" void kernel_launch(void* const* d_in, const int* in_sizes, int n_in,
                              void* d_out, int out_size, void* d_ws, size_t ws_size,
                              hipStream_t stream) {
    char* ws = (char*)d_ws;
    u16* qkv     = (u16*)(ws);                        // 231,211,008 B
    u16* xbf     = (u16*)(ws + 231211008);            //  77,070,336 B (= attnout)
    u16* attnout = xbf;
    u16* wqkv_bf = (u16*)(ws + 308281344);            //   3,538,944 B
    u16* wproj_bf= (u16*)(ws + 311820288);            //   1,179,648 B
    u16* rpb     = (u16*)(ws + 312999936);            //   1,038,336 B
    u16* qb_bf   = (u16*)(ws + 314038272);
    u16* vb_bf   = (u16*)(ws + 314039808);
    u16* pb_bf   = (u16*)(ws + 314041344);
    u16* tbl_bf  = (u16*)(ws + 314042880);
    int* flag    = (int*)(ws + 314060384);

    detect_kernel<<<1, 64, 0, stream>>>((const u16*)d_in[0], flag);
    convert_kernel<<<4096, 256, 0, stream>>>(d_in[0], xbf,      16 * 3136 * 768, flag);
    convert_kernel<<<1728, 256, 0, stream>>>(d_in[1], wqkv_bf,  2304 * 768,      flag);
    convert_kernel<<< 576, 256, 0, stream>>>(d_in[5], wproj_bf, 768 * 768,       flag);
    convert_kernel<<<   1, 256, 0, stream>>>(d_in[2], qb_bf,    768,             flag);
    convert_kernel<<<   1, 256, 0, stream>>>(d_in[3], vb_bf,    768,             flag);
    convert_kernel<<<   1, 256, 0, stream>>>(d_in[6], pb_bf,    768,             flag);
    convert_kernel<<<   9, 256, 0, stream>>>(d_in[4], tbl_bf,   729 * 12,        flag);

    rpb_prep<<<2028, 256, 0, stream>>>(tbl_bf, rpb);
    gemm_kernel<0, 2304><<<dim3(18, 392), 256, 0, stream>>>(
        xbf, wqkv_bf, qb_bf, vb_bf, qkv, flag);
    attn_kernel<<<3072, 256, 0, stream>>>(qkv, rpb, attnout);
    gemm_kernel<1, 768><<<dim3(6, 392), 256, 0, stream>>>(
        attnout, wproj_bf, pb_bf, pb_bf, d_out, flag);
}